// Round 1
// baseline (323.018 us; speedup 1.0000x reference)
//
#include <hip/hip_runtime.h>
#include <hip/hip_bf16.h>
#include <hip/hip_fp16.h>

// CrossAttention fused pipeline for MI355X (gfx950).
// B=2, S=2048, D=1024, H=16, dh=64. Internal compute fp16 + f32 MFMA accum.

#define D_MODEL 1024
#define NHEAD   16
#define DH      64
#define SEQ     2048
#define BATCH   2
#define MTOT    (BATCH*SEQ)   // 4096

typedef _Float16 f16;
typedef _Float16 f16x8 __attribute__((ext_vector_type(8)));
typedef _Float16 f16x4 __attribute__((ext_vector_type(4)));
typedef float    f32x4 __attribute__((ext_vector_type(4)));

// ---- async global->LDS (16B per lane). LDS dest must be linear: base + lane*16.
__device__ __forceinline__ void gload_lds16(const void* g, void* l) {
  typedef __attribute__((address_space(1))) const unsigned int* gp_t;
  typedef __attribute__((address_space(3))) unsigned int*       lp_t;
  __builtin_amdgcn_global_load_lds((gp_t)g, (lp_t)l, 16, 0, 0);
}

// ---------------- f32 -> f16 convert ----------------
__global__ __launch_bounds__(256)
void cvt_kernel(const float* __restrict__ src, f16* __restrict__ dst, int n4) {
  int i = blockIdx.x * blockDim.x + threadIdx.x;
  if (i < n4) {
    float4 v = reinterpret_cast<const float4*>(src)[i];
    f16x4 h;
    h[0] = (f16)v.x; h[1] = (f16)v.y; h[2] = (f16)v.z; h[3] = (f16)v.w;
    reinterpret_cast<f16x4*>(dst)[i] = h;
  }
}

// ---------------- QKV projection GEMM ----------------
// C[r][c] = sum_k A[r][k] * W[c][k] + bias[c]
// A: [4096][1024] f16, W: [1024][1024] f16 (torch [out,in]).
// mode 0: Q -> [4096][1024]; mode 1: K -> [4096][1024];
// mode 2: V -> transposed Vt[b][h][dd][s]  ([B*H][64][2048])
__global__ __launch_bounds__(256)
void qkv_gemm(const f16* __restrict__ dec_h, const f16* __restrict__ enc_h,
              const f16* __restrict__ Wqh, const f16* __restrict__ Wkh, const f16* __restrict__ Wvh,
              const float* __restrict__ bq, const float* __restrict__ bk, const float* __restrict__ bv,
              f16* __restrict__ Qh, f16* __restrict__ Kh, f16* __restrict__ Vth)
{
  __shared__ f16 Ash[128 * 64];   // [row][k]  row stride 128B
  __shared__ f16 Bsh[128 * 64];   // [n][k]

  const int mode = blockIdx.z;
  const f16* A     = (mode == 0) ? dec_h : enc_h;
  const f16* W     = (mode == 0) ? Wqh : (mode == 1) ? Wkh : Wvh;
  const float* bias= (mode == 0) ? bq  : (mode == 1) ? bk  : bv;
  f16* out         = (mode == 0) ? Qh  : (mode == 1) ? Kh  : Vth;

  const int tid  = threadIdx.x;
  const int lane = tid & 63;
  const int wave = tid >> 6;
  const int wr = wave >> 1, wc = wave & 1;   // 2x2 waves, each owns 64x64 of C
  const int bm = blockIdx.x, bn = blockIdx.y;
  const int l15 = lane & 15, lg = lane >> 4;

  f32x4 acc[4][4] = {};

  for (int k0 = 0; k0 < D_MODEL; k0 += 64) {
    __syncthreads();
#pragma unroll
    for (int it = 0; it < 4; ++it) {
      int off = it * 4096 + tid * 16;      // byte offset in 16KB tile
      int row = off >> 7, colb = off & 127;
      gload_lds16((const char*)A + (size_t)(bm*128 + row) * 2048 + k0*2 + colb,
                  (char*)Ash + off);
      gload_lds16((const char*)W + (size_t)(bn*128 + row) * 2048 + k0*2 + colb,
                  (char*)Bsh + off);
    }
    __syncthreads();
#pragma unroll
    for (int ks = 0; ks < 2; ++ks) {
      f16x8 af[4], bf[4];
#pragma unroll
      for (int m = 0; m < 4; ++m)
        af[m] = *reinterpret_cast<const f16x8*>((const char*)Ash + (wr*64 + m*16 + l15)*128 + ks*64 + lg*16);
#pragma unroll
      for (int n = 0; n < 4; ++n)
        bf[n] = *reinterpret_cast<const f16x8*>((const char*)Bsh + (wc*64 + n*16 + l15)*128 + ks*64 + lg*16);
#pragma unroll
      for (int m = 0; m < 4; ++m)
#pragma unroll
        for (int n = 0; n < 4; ++n)
          acc[m][n] = __builtin_amdgcn_mfma_f32_16x16x32_f16(af[m], bf[n], acc[m][n], 0, 0, 0);
    }
  }

  // epilogue: C/D layout col = lane&15, row = (lane>>4)*4 + j   [m89-verified]
#pragma unroll
  for (int m = 0; m < 4; ++m) {
    int rowg = bm*128 + wr*64 + m*16 + lg*4;
#pragma unroll
    for (int n = 0; n < 4; ++n) {
      int colg = bn*128 + wc*64 + n*16 + l15;
      float bv = bias[colg];
#pragma unroll
      for (int j = 0; j < 4; ++j) {
        float v = acc[m][n][j] + bv;
        int r = rowg + j;
        if (mode < 2) {
          out[(size_t)r * D_MODEL + colg] = (f16)v;
        } else {
          int b = r >> 11, s = r & 2047;
          int h = colg >> 6, dd = colg & 63;
          out[(((size_t)((b*NHEAD + h)*DH + dd)) << 11) + s] = (f16)v;
        }
      }
    }
  }
}

// ---------------- flash attention ----------------
// Q,K: [4096][1024] f16 (head h at col h*64). Vt: [B*H][64][2048] f16.
// Z out: [B*H][2048][64] f32 (unnormalized layout consumed by LN gather).
// NOTE: reference applies NO 1/sqrt(dh) scaling.
__global__ __launch_bounds__(256)
void attn_kernel(const f16* __restrict__ Q, const f16* __restrict__ K,
                 const f16* __restrict__ Vt, float* __restrict__ Z)
{
  __shared__ f16 Klds[64 * 64];       // [kv][d]
  __shared__ f16 Vlds[64 * 64];       // [dd][kv]  (Vt tile)
  __shared__ f16 Plds[4][16 * 64];    // per-wave [q][kk]

  const int tid = threadIdx.x, lane = tid & 63, wave = tid >> 6;
  const int l15 = lane & 15, lg = lane >> 4;
  const int qb = blockIdx.x;          // 0..31 (q block of 64)
  const int bh = blockIdx.y;          // 0..31
  const int b = bh >> 4, h = bh & 15;

  // Q fragments (A operand): lane holds Q[q0+l15][ks*32 + lg*8 + 0..7]
  const int qrow = qb*64 + wave*16 + l15;
  f16x8 qf[2];
#pragma unroll
  for (int ks = 0; ks < 2; ++ks)
    qf[ks] = *reinterpret_cast<const f16x8*>(Q + ((size_t)(b*SEQ + qrow)*D_MODEL + h*DH + ks*32 + lg*8));

  f32x4 oacc[4] = {};
  float mrun[4], lrun[4];
#pragma unroll
  for (int j = 0; j < 4; ++j) { mrun[j] = -__builtin_inff(); lrun[j] = 0.f; }

  const char* Kbase = (const char*)(K  + ((size_t)b*SEQ*D_MODEL + h*DH));   // + kv*2048B
  const char* Vbase = (const char*)(Vt + ((size_t)bh*DH*SEQ));              // + dd*4096B + s*2B

  for (int kb = 0; kb < SEQ/64; ++kb) {
    __syncthreads();
#pragma unroll
    for (int it = 0; it < 2; ++it) {
      int off = it * 4096 + tid * 16;
      int row = off >> 7, colb = off & 127;
      gload_lds16(Kbase + (size_t)(kb*64 + row) * 2048 + colb, (char*)Klds + off);
      gload_lds16(Vbase + (size_t)row * 4096 + kb*128 + colb,  (char*)Vlds + off);
    }
    __syncthreads();

    // S = Q K^T   (B operand = K^T: lane holds K[n*16+l15][ks*32+lg*8+0..7])
    f32x4 sacc[4] = {};
#pragma unroll
    for (int ks = 0; ks < 2; ++ks) {
#pragma unroll
      for (int n = 0; n < 4; ++n) {
        f16x8 kf = *reinterpret_cast<const f16x8*>((const char*)Klds + (n*16 + l15)*128 + ks*64 + lg*16);
        sacc[n] = __builtin_amdgcn_mfma_f32_16x16x32_f16(qf[ks], kf, sacc[n], 0, 0, 0);
      }
    }

    // online softmax; row q = lg*4+j lives in the 16 lanes of group lg
    float mt[4], rs[4], p[4][4], scale[4];
#pragma unroll
    for (int j = 0; j < 4; ++j)
      mt[j] = fmaxf(fmaxf(sacc[0][j], sacc[1][j]), fmaxf(sacc[2][j], sacc[3][j]));
#pragma unroll
    for (int off = 1; off < 16; off <<= 1)
#pragma unroll
      for (int j = 0; j < 4; ++j) mt[j] = fmaxf(mt[j], __shfl_xor(mt[j], off));
#pragma unroll
    for (int j = 0; j < 4; ++j) {
      float mn = fmaxf(mrun[j], mt[j]);
      scale[j] = __expf(mrun[j] - mn);
      mrun[j] = mn;
      rs[j] = 0.f;
#pragma unroll
      for (int n = 0; n < 4; ++n) { p[n][j] = __expf(sacc[n][j] - mn); rs[j] += p[n][j]; }
    }
#pragma unroll
    for (int off = 1; off < 16; off <<= 1)
#pragma unroll
      for (int j = 0; j < 4; ++j) rs[j] += __shfl_xor(rs[j], off);
#pragma unroll
    for (int j = 0; j < 4; ++j) lrun[j] = lrun[j]*scale[j] + rs[j];
#pragma unroll
    for (int n = 0; n < 4; ++n)
#pragma unroll
      for (int j = 0; j < 4; ++j) oacc[n][j] *= scale[j];

    // P -> per-wave LDS [q][kk] so it can be re-read as the PV A-operand
#pragma unroll
    for (int n = 0; n < 4; ++n)
#pragma unroll
      for (int j = 0; j < 4; ++j)
        Plds[wave][(lg*4 + j)*64 + l15 + n*16] = (f16)p[n][j];

    // O += P @ V  (B operand from Vt tile: lane holds V[ks*32+lg*8+i][n*16+l15])
#pragma unroll
    for (int ks = 0; ks < 2; ++ks) {
      f16x8 pf = *reinterpret_cast<const f16x8*>(&Plds[wave][l15*64 + ks*32 + lg*8]);
#pragma unroll
      for (int n = 0; n < 4; ++n) {
        f16x8 vf = *reinterpret_cast<const f16x8*>((const char*)Vlds + (n*16 + l15)*128 + ks*64 + lg*16);
        oacc[n] = __builtin_amdgcn_mfma_f32_16x16x32_f16(pf, vf, oacc[n], 0, 0, 0);
      }
    }
  }

  // normalize + store z (f32)
#pragma unroll
  for (int n = 0; n < 4; ++n)
#pragma unroll
    for (int j = 0; j < 4; ++j) {
      float v = oacc[n][j] / lrun[j];
      Z[((size_t)bh*SEQ + qb*64 + wave*16 + lg*4 + j)*DH + n*16 + l15] = v;
    }
}

// ---------------- residual + LayerNorm with the raw-memory reshape gather ----------------
// x[b,sq,d] = Z[b*16 + (sq>>7)][((sq&127)<<4) | (d>>6)][d&63] + decoded[b,sq,d]
__global__ __launch_bounds__(256)
void ln_kernel(const float* __restrict__ Z, const float* __restrict__ dec,
               const float* __restrict__ gamma, const float* __restrict__ beta,
               float* __restrict__ out)
{
  const int row = blockIdx.x;            // 0..4095 (b*2048 + sq)
  const int b = row >> 11, sq = row & 2047;
  const int h = sq >> 7;
  const int qbase = (sq & 127) << 4;
  const int t = threadIdx.x;
  const int d = t * 4;
  const int qi = qbase + (d >> 6);

  float4 z4 = *reinterpret_cast<const float4*>(Z + ((size_t)(b*NHEAD + h)*SEQ + qi)*DH + (d & 63));
  float4 dv = *reinterpret_cast<const float4*>(dec + (size_t)row*D_MODEL + d);
  float x0 = z4.x + dv.x, x1 = z4.y + dv.y, x2 = z4.z + dv.z, x3 = z4.w + dv.w;

  float s  = x0 + x1 + x2 + x3;
  float ss = x0*x0 + x1*x1 + x2*x2 + x3*x3;
#pragma unroll
  for (int off = 1; off < 64; off <<= 1) { s += __shfl_xor(s, off); ss += __shfl_xor(ss, off); }

  __shared__ float red[8];
  int wave = t >> 6, lane = t & 63;
  if (lane == 0) { red[wave] = s; red[wave + 4] = ss; }
  __syncthreads();
  s  = red[0] + red[1] + red[2] + red[3];
  ss = red[4] + red[5] + red[6] + red[7];

  float mean = s * (1.f/1024.f);
  float var  = ss * (1.f/1024.f) - mean*mean;
  float rstd = rsqrtf(var + 1e-5f);

  float4 g4 = *reinterpret_cast<const float4*>(gamma + d);
  float4 b4 = *reinterpret_cast<const float4*>(beta + d);
  float4 o;
  o.x = (x0 - mean)*rstd*g4.x + b4.x;
  o.y = (x1 - mean)*rstd*g4.y + b4.y;
  o.z = (x2 - mean)*rstd*g4.z + b4.z;
  o.w = (x3 - mean)*rstd*g4.w + b4.w;
  *reinterpret_cast<float4*>(out + (size_t)row*D_MODEL + d) = o;
}

// ---------------- launch ----------------
extern "C" void kernel_launch(void* const* d_in, const int* in_sizes, int n_in,
                              void* d_out, int out_size, void* d_ws, size_t ws_size,
                              hipStream_t stream) {
  const float* enc   = (const float*)d_in[0];
  const float* dec   = (const float*)d_in[1];
  const float* Wq    = (const float*)d_in[2];
  const float* bq    = (const float*)d_in[3];
  const float* Wk    = (const float*)d_in[4];
  const float* bk    = (const float*)d_in[5];
  const float* Wv    = (const float*)d_in[6];
  const float* bv    = (const float*)d_in[7];
  const float* gamma = (const float*)d_in[8];
  const float* beta  = (const float*)d_in[9];
  float* out = (float*)d_out;
  uint8_t* ws = (uint8_t*)d_ws;

  // workspace layout (62 MB total)
  f16*  enc_h = (f16*)(ws);                       // 8 MB
  f16*  dec_h = (f16*)(ws + (8u  << 20));         // 8 MB
  f16*  Wq_h  = (f16*)(ws + (16u << 20));         // 2 MB
  f16*  Wk_h  = (f16*)(ws + (18u << 20));         // 2 MB
  f16*  Wv_h  = (f16*)(ws + (20u << 20));         // 2 MB
  f16*  Qh    = (f16*)(ws + (22u << 20));         // 8 MB
  f16*  Kh    = (f16*)(ws + (30u << 20));         // 8 MB
  f16*  Vth   = (f16*)(ws + (38u << 20));         // 8 MB  [B*H][64][2048]
  float* Z    = (float*)(ws + (46u << 20));       // 16 MB [B*H][2048][64]

  const int nbig = MTOT * D_MODEL / 4;            // 1M float4 chunks
  const int nw   = D_MODEL * D_MODEL / 4;         // 256K
  cvt_kernel<<<nbig/256, 256, 0, stream>>>(enc, enc_h, nbig);
  cvt_kernel<<<nbig/256, 256, 0, stream>>>(dec, dec_h, nbig);
  cvt_kernel<<<nw/256,  256, 0, stream>>>(Wq, Wq_h, nw);
  cvt_kernel<<<nw/256,  256, 0, stream>>>(Wk, Wk_h, nw);
  cvt_kernel<<<nw/256,  256, 0, stream>>>(Wv, Wv_h, nw);

  qkv_gemm<<<dim3(MTOT/128, D_MODEL/128, 3), 256, 0, stream>>>(
      dec_h, enc_h, Wq_h, Wk_h, Wv_h, bq, bk, bv, Qh, Kh, Vth);

  attn_kernel<<<dim3(SEQ/64, BATCH*NHEAD), 256, 0, stream>>>(Qh, Kh, Vth, Z);

  ln_kernel<<<MTOT, 256, 0, stream>>>(Z, dec, gamma, beta, out);
}

// Round 3
// 288.860 us; speedup vs baseline: 1.1183x; 1.1183x over previous
//
#include <hip/hip_runtime.h>
#include <hip/hip_bf16.h>
#include <hip/hip_fp16.h>

// CrossAttention fused pipeline for MI355X (gfx950).
// B=2, S=2048, D=1024, H=16, dh=64. Internal compute fp16 + f32 MFMA accum.

#define D_MODEL 1024
#define NHEAD   16
#define DH      64
#define SEQ     2048
#define BATCH   2
#define MTOT    (BATCH*SEQ)   // 4096

typedef _Float16 f16;
typedef _Float16 f16x8 __attribute__((ext_vector_type(8)));
typedef _Float16 f16x4 __attribute__((ext_vector_type(4)));
typedef float    f32x4 __attribute__((ext_vector_type(4)));

// ---- async global->LDS (16B per lane). LDS dest must be linear: base + lane*16.
__device__ __forceinline__ void gload_lds16(const void* g, void* l) {
  typedef __attribute__((address_space(1))) const unsigned int* gp_t;
  typedef __attribute__((address_space(3))) unsigned int*       lp_t;
  __builtin_amdgcn_global_load_lds((gp_t)g, (lp_t)l, 16, 0, 0);
}

// ---------------- f32 -> f16 convert ----------------
__global__ __launch_bounds__(256)
void cvt_kernel(const float* __restrict__ src, f16* __restrict__ dst, int n4) {
  int i = blockIdx.x * blockDim.x + threadIdx.x;
  if (i < n4) {
    float4 v = reinterpret_cast<const float4*>(src)[i];
    f16x4 h;
    h[0] = (f16)v.x; h[1] = (f16)v.y; h[2] = (f16)v.z; h[3] = (f16)v.w;
    reinterpret_cast<f16x4*>(dst)[i] = h;
  }
}

// ---------------- QKV projection GEMM ----------------
// C[r][c] = sum_k A[r][k] * W[c][k] + bias[c]
// A: [4096][1024] f16, W: [1024][1024] f16 (torch [out,in]).
// mode 0: Q -> [4096][1024]; mode 1: K -> [4096][1024];
// mode 2: V -> transposed Vt[b][h][dd][s]  ([B*H][64][2048])
__global__ __launch_bounds__(256)
void qkv_gemm(const f16* __restrict__ dec_h, const f16* __restrict__ enc_h,
              const f16* __restrict__ Wqh, const f16* __restrict__ Wkh, const f16* __restrict__ Wvh,
              const float* __restrict__ bq, const float* __restrict__ bk, const float* __restrict__ bv,
              f16* __restrict__ Qh, f16* __restrict__ Kh, f16* __restrict__ Vth)
{
  __shared__ f16 Ash[128 * 64];   // [row][k]  row stride 128B
  __shared__ f16 Bsh[128 * 64];   // [n][k]

  const int mode = blockIdx.z;
  const f16* A     = (mode == 0) ? dec_h : enc_h;
  const f16* W     = (mode == 0) ? Wqh : (mode == 1) ? Wkh : Wvh;
  const float* bias= (mode == 0) ? bq  : (mode == 1) ? bk  : bv;
  f16* out         = (mode == 0) ? Qh  : (mode == 1) ? Kh  : Vth;

  const int tid  = threadIdx.x;
  const int lane = tid & 63;
  const int wave = tid >> 6;
  const int wr = wave >> 1, wc = wave & 1;   // 2x2 waves, each owns 64x64 of C
  const int bm = blockIdx.x, bn = blockIdx.y;
  const int l15 = lane & 15, lg = lane >> 4;

  f32x4 acc[4][4] = {};

  for (int k0 = 0; k0 < D_MODEL; k0 += 64) {
    __syncthreads();
#pragma unroll
    for (int it = 0; it < 4; ++it) {
      int off = it * 4096 + tid * 16;      // byte offset in 16KB tile
      int row = off >> 7, colb = off & 127;
      gload_lds16((const char*)A + (size_t)(bm*128 + row) * 2048 + k0*2 + colb,
                  (char*)Ash + off);
      gload_lds16((const char*)W + (size_t)(bn*128 + row) * 2048 + k0*2 + colb,
                  (char*)Bsh + off);
    }
    __syncthreads();
#pragma unroll
    for (int ks = 0; ks < 2; ++ks) {
      f16x8 af[4], bf[4];
#pragma unroll
      for (int m = 0; m < 4; ++m)
        af[m] = *reinterpret_cast<const f16x8*>((const char*)Ash + (wr*64 + m*16 + l15)*128 + ks*64 + lg*16);
#pragma unroll
      for (int n = 0; n < 4; ++n)
        bf[n] = *reinterpret_cast<const f16x8*>((const char*)Bsh + (wc*64 + n*16 + l15)*128 + ks*64 + lg*16);
#pragma unroll
      for (int m = 0; m < 4; ++m)
#pragma unroll
        for (int n = 0; n < 4; ++n)
          acc[m][n] = __builtin_amdgcn_mfma_f32_16x16x32_f16(af[m], bf[n], acc[m][n], 0, 0, 0);
    }
  }

  // epilogue: C/D layout col = lane&15, row = (lane>>4)*4 + j   [m89-verified]
#pragma unroll
  for (int m = 0; m < 4; ++m) {
    int rowg = bm*128 + wr*64 + m*16 + lg*4;
#pragma unroll
    for (int n = 0; n < 4; ++n) {
      int colg = bn*128 + wc*64 + n*16 + l15;
      float bv = bias[colg];
#pragma unroll
      for (int j = 0; j < 4; ++j) {
        float v = acc[m][n][j] + bv;
        int r = rowg + j;
        if (mode < 2) {
          out[(size_t)r * D_MODEL + colg] = (f16)v;
        } else {
          int b = r >> 11, s = r & 2047;
          int h = colg >> 6, dd = colg & 63;
          out[(((size_t)((b*NHEAD + h)*DH + dd)) << 11) + s] = (f16)v;
        }
      }
    }
  }
}

// ---------------- flash attention (single-buffer two-barrier, XOR-swizzled LDS) ----------------
// Q,K: [4096][1024] f16 (head h at col h*64). Vt: [B*H][64][2048] f16.
// Z out: [B*H][2048][64] f32 (unnormalized layout consumed by LN gather).
// NOTE: reference applies NO 1/sqrt(dh) scaling.
//
// Schedule: round-1's proven race-free two-barrier loop (barrier; STAGE;
// vmcnt(0)+barrier; compute). Only change vs round 1 is the T2 XOR swizzle:
// dest of global_load_lds stays LINEAR; the global source 128B-row offset is
// XOR'd with ((row&7)<<4); every ds access applies the same XOR (rule #21).
__global__ __launch_bounds__(256)
void attn_kernel(const f16* __restrict__ Q, const f16* __restrict__ K,
                 const f16* __restrict__ Vt, float* __restrict__ Z)
{
  __shared__ f16 Klds[64 * 64];       // [kv][d]   row stride 128B, swizzled
  __shared__ f16 Vlds[64 * 64];       // [dd][kv]  row stride 128B, swizzled
  __shared__ f16 Plds[4][16 * 64];    // per-wave [q][kk], swizzled

  const int tid = threadIdx.x, lane = tid & 63, wave = tid >> 6;
  const int l15 = lane & 15, lg = lane >> 4;
  const int qb = blockIdx.x;          // 0..31 (q block of 64)
  const int bh = blockIdx.y;          // 0..31
  const int b = bh >> 4, h = bh & 15;

  // Q fragments (A operand): lane holds Q[q0+l15][ks*32 + lg*8 + 0..7]
  const int qrow = qb*64 + wave*16 + l15;
  f16x8 qf[2];
#pragma unroll
  for (int ks = 0; ks < 2; ++ks)
    qf[ks] = *reinterpret_cast<const f16x8*>(Q + ((size_t)(b*SEQ + qrow)*D_MODEL + h*DH + ks*32 + lg*8));

  f32x4 oacc[4] = {};
  float mrun[4], lrun[4];
#pragma unroll
  for (int j = 0; j < 4; ++j) { mrun[j] = -__builtin_inff(); lrun[j] = 0.f; }

  const char* Kbase = (const char*)(K  + ((size_t)b*SEQ*D_MODEL + h*DH));   // + kv*2048B
  const char* Vbase = (const char*)(Vt + ((size_t)bh*DH*SEQ));              // + dd*4096B + s*2B

  for (int kb = 0; kb < SEQ/64; ++kb) {
    __syncthreads();                  // all reads of previous tile complete
#pragma unroll
    for (int it = 0; it < 2; ++it) {
      int off = it * 4096 + tid * 16;
      int row = off >> 7, colb = off & 127;
      int scol = colb ^ ((row & 7) << 4);     // inverse-swizzled global source
      gload_lds16(Kbase + (size_t)(kb*64 + row) * 2048 + scol, (char*)Klds + off);
      gload_lds16(Vbase + (size_t)row * 4096 + kb*128 + scol,  (char*)Vlds + off);
    }
    asm volatile("s_waitcnt vmcnt(0)" ::: "memory");
    __syncthreads();                  // tile resident for all waves

    // S = Q K^T   (B operand = K^T: lane holds K[n*16+l15][ks*32+lg*8+0..7])
    f32x4 sacc[4] = {};
#pragma unroll
    for (int ks = 0; ks < 2; ++ks) {
#pragma unroll
      for (int n = 0; n < 4; ++n) {
        int r = n*16 + l15;
        f16x8 kf = *reinterpret_cast<const f16x8*>(
            (const char*)Klds + r*128 + ((ks*64 + lg*16) ^ ((r & 7) << 4)));
        sacc[n] = __builtin_amdgcn_mfma_f32_16x16x32_f16(qf[ks], kf, sacc[n], 0, 0, 0);
      }
    }

    // online softmax; row q = lg*4+j lives in the 16 lanes of group lg
    float mt[4], rs[4], p[4][4], scale[4];
#pragma unroll
    for (int j = 0; j < 4; ++j)
      mt[j] = fmaxf(fmaxf(sacc[0][j], sacc[1][j]), fmaxf(sacc[2][j], sacc[3][j]));
#pragma unroll
    for (int off = 1; off < 16; off <<= 1)
#pragma unroll
      for (int j = 0; j < 4; ++j) mt[j] = fmaxf(mt[j], __shfl_xor(mt[j], off));
#pragma unroll
    for (int j = 0; j < 4; ++j) {
      float mn = fmaxf(mrun[j], mt[j]);
      scale[j] = __expf(mrun[j] - mn);
      mrun[j] = mn;
      rs[j] = 0.f;
#pragma unroll
      for (int n = 0; n < 4; ++n) { p[n][j] = __expf(sacc[n][j] - mn); rs[j] += p[n][j]; }
    }
#pragma unroll
    for (int off = 1; off < 16; off <<= 1)
#pragma unroll
      for (int j = 0; j < 4; ++j) rs[j] += __shfl_xor(rs[j], off);
#pragma unroll
    for (int j = 0; j < 4; ++j) lrun[j] = lrun[j]*scale[j] + rs[j];
#pragma unroll
    for (int n = 0; n < 4; ++n)
#pragma unroll
      for (int j = 0; j < 4; ++j) oacc[n][j] *= scale[j];

    // P -> per-wave LDS [q][kk] (swizzled) so it can be re-read as the PV A-operand
#pragma unroll
    for (int n = 0; n < 4; ++n)
#pragma unroll
      for (int j = 0; j < 4; ++j) {
        int q = lg*4 + j;
        *reinterpret_cast<f16*>((char*)&Plds[wave][0] + q*128 +
                                (((l15 + n*16)*2) ^ ((q & 7) << 4))) = (f16)p[n][j];
      }

    // O += P @ V  (B operand from Vt tile: lane holds V[ks*32+lg*8+i][n*16+l15])
#pragma unroll
    for (int ks = 0; ks < 2; ++ks) {
      f16x8 pf = *reinterpret_cast<const f16x8*>(
          (const char*)&Plds[wave][0] + l15*128 + ((ks*64 + lg*16) ^ ((l15 & 7) << 4)));
#pragma unroll
      for (int n = 0; n < 4; ++n) {
        int r = n*16 + l15;
        f16x8 vf = *reinterpret_cast<const f16x8*>(
            (const char*)Vlds + r*128 + ((ks*64 + lg*16) ^ ((r & 7) << 4)));
        oacc[n] = __builtin_amdgcn_mfma_f32_16x16x32_f16(pf, vf, oacc[n], 0, 0, 0);
      }
    }
  }

  // normalize + store z (f32)
#pragma unroll
  for (int n = 0; n < 4; ++n)
#pragma unroll
    for (int j = 0; j < 4; ++j) {
      float v = oacc[n][j] / lrun[j];
      Z[((size_t)bh*SEQ + qb*64 + wave*16 + lg*4 + j)*DH + n*16 + l15] = v;
    }
}

// ---------------- residual + LayerNorm with the raw-memory reshape gather ----------------
// x[b,sq,d] = Z[b*16 + (sq>>7)][((sq&127)<<4) | (d>>6)][d&63] + decoded[b,sq,d]
__global__ __launch_bounds__(256)
void ln_kernel(const float* __restrict__ Z, const float* __restrict__ dec,
               const float* __restrict__ gamma, const float* __restrict__ beta,
               float* __restrict__ out)
{
  const int row = blockIdx.x;            // 0..4095 (b*2048 + sq)
  const int b = row >> 11, sq = row & 2047;
  const int h = sq >> 7;
  const int qbase = (sq & 127) << 4;
  const int t = threadIdx.x;
  const int d = t * 4;
  const int qi = qbase + (d >> 6);

  float4 z4 = *reinterpret_cast<const float4*>(Z + ((size_t)(b*NHEAD + h)*SEQ + qi)*DH + (d & 63));
  float4 dv = *reinterpret_cast<const float4*>(dec + (size_t)row*D_MODEL + d);
  float x0 = z4.x + dv.x, x1 = z4.y + dv.y, x2 = z4.z + dv.z, x3 = z4.w + dv.w;

  float s  = x0 + x1 + x2 + x3;
  float ss = x0*x0 + x1*x1 + x2*x2 + x3*x3;
#pragma unroll
  for (int off = 1; off < 64; off <<= 1) { s += __shfl_xor(s, off); ss += __shfl_xor(ss, off); }

  __shared__ float red[8];
  int wave = t >> 6, lane = t & 63;
  if (lane == 0) { red[wave] = s; red[wave + 4] = ss; }
  __syncthreads();
  s  = red[0] + red[1] + red[2] + red[3];
  ss = red[4] + red[5] + red[6] + red[7];

  float mean = s * (1.f/1024.f);
  float var  = ss * (1.f/1024.f) - mean*mean;
  float rstd = rsqrtf(var + 1e-5f);

  float4 g4 = *reinterpret_cast<const float4*>(gamma + d);
  float4 b4 = *reinterpret_cast<const float4*>(beta + d);
  float4 o;
  o.x = (x0 - mean)*rstd*g4.x + b4.x;
  o.y = (x1 - mean)*rstd*g4.y + b4.y;
  o.z = (x2 - mean)*rstd*g4.z + b4.z;
  o.w = (x3 - mean)*rstd*g4.w + b4.w;
  *reinterpret_cast<float4*>(out + (size_t)row*D_MODEL + d) = o;
}

// ---------------- launch ----------------
extern "C" void kernel_launch(void* const* d_in, const int* in_sizes, int n_in,
                              void* d_out, int out_size, void* d_ws, size_t ws_size,
                              hipStream_t stream) {
  const float* enc   = (const float*)d_in[0];
  const float* dec   = (const float*)d_in[1];
  const float* Wq    = (const float*)d_in[2];
  const float* bq    = (const float*)d_in[3];
  const float* Wk    = (const float*)d_in[4];
  const float* bk    = (const float*)d_in[5];
  const float* Wv    = (const float*)d_in[6];
  const float* bv    = (const float*)d_in[7];
  const float* gamma = (const float*)d_in[8];
  const float* beta  = (const float*)d_in[9];
  float* out = (float*)d_out;
  uint8_t* ws = (uint8_t*)d_ws;

  // workspace layout (62 MB total)
  f16*  enc_h = (f16*)(ws);                       // 8 MB
  f16*  dec_h = (f16*)(ws + (8u  << 20));         // 8 MB
  f16*  Wq_h  = (f16*)(ws + (16u << 20));         // 2 MB
  f16*  Wk_h  = (f16*)(ws + (18u << 20));         // 2 MB
  f16*  Wv_h  = (f16*)(ws + (20u << 20));         // 2 MB
  f16*  Qh    = (f16*)(ws + (22u << 20));         // 8 MB
  f16*  Kh    = (f16*)(ws + (30u << 20));         // 8 MB
  f16*  Vth   = (f16*)(ws + (38u << 20));         // 8 MB  [B*H][64][2048]
  float* Z    = (float*)(ws + (46u << 20));       // 16 MB [B*H][2048][64]

  const int nbig = MTOT * D_MODEL / 4;            // 1M float4 chunks
  const int nw   = D_MODEL * D_MODEL / 4;         // 256K
  cvt_kernel<<<nbig/256, 256, 0, stream>>>(enc, enc_h, nbig);
  cvt_kernel<<<nbig/256, 256, 0, stream>>>(dec, dec_h, nbig);
  cvt_kernel<<<nw/256,  256, 0, stream>>>(Wq, Wq_h, nw);
  cvt_kernel<<<nw/256,  256, 0, stream>>>(Wk, Wk_h, nw);
  cvt_kernel<<<nw/256,  256, 0, stream>>>(Wv, Wv_h, nw);

  qkv_gemm<<<dim3(MTOT/128, D_MODEL/128, 3), 256, 0, stream>>>(
      dec_h, enc_h, Wq_h, Wk_h, Wv_h, bq, bk, bv, Qh, Kh, Vth);

  attn_kernel<<<dim3(SEQ/64, BATCH*NHEAD), 256, 0, stream>>>(Qh, Kh, Vth, Z);

  ln_kernel<<<MTOT, 256, 0, stream>>>(Z, dec, gamma, beta, out);
}

// Round 4
// 221.223 us; speedup vs baseline: 1.4602x; 1.3057x over previous
//
#include <hip/hip_runtime.h>
#include <hip/hip_bf16.h>
#include <hip/hip_fp16.h>

// CrossAttention fused pipeline for MI355X (gfx950).
// B=2, S=2048, D=1024, H=16, dh=64. Internal compute fp16 + f32 MFMA accum.

#define D_MODEL 1024
#define NHEAD   16
#define DH      64
#define SEQ     2048
#define BATCH   2
#define MTOT    (BATCH*SEQ)   // 4096

typedef _Float16 f16;
typedef _Float16 f16x8 __attribute__((ext_vector_type(8)));
typedef _Float16 f16x4 __attribute__((ext_vector_type(4)));
typedef float    f32x4 __attribute__((ext_vector_type(4)));

// ---- async global->LDS (16B per lane). LDS dest must be linear: base + lane*16.
__device__ __forceinline__ void gload_lds16(const void* g, void* l) {
  typedef __attribute__((address_space(1))) const unsigned int* gp_t;
  typedef __attribute__((address_space(3))) unsigned int*       lp_t;
  __builtin_amdgcn_global_load_lds((gp_t)g, (lp_t)l, 16, 0, 0);
}

// ---------------- f32 -> f16 convert (all 5 tensors in one launch) ----------------
__global__ __launch_bounds__(256)
void cvt5_kernel(const float* __restrict__ s0, f16* __restrict__ d0, int n0,
                 const float* __restrict__ s1, f16* __restrict__ d1, int n1,
                 const float* __restrict__ s2, f16* __restrict__ d2, int n2,
                 const float* __restrict__ s3, f16* __restrict__ d3, int n3,
                 const float* __restrict__ s4, f16* __restrict__ d4, int n4_) {
  const float* s; f16* d; int n;
  switch (blockIdx.y) {
    case 0: s = s0; d = d0; n = n0; break;
    case 1: s = s1; d = d1; n = n1; break;
    case 2: s = s2; d = d2; n = n2; break;
    case 3: s = s3; d = d3; n = n3; break;
    default: s = s4; d = d4; n = n4_; break;
  }
  int i = blockIdx.x * blockDim.x + threadIdx.x;
  if (i < n) {
    float4 v = reinterpret_cast<const float4*>(s)[i];
    f16x4 h;
    h[0] = (f16)v.x; h[1] = (f16)v.y; h[2] = (f16)v.z; h[3] = (f16)v.w;
    reinterpret_cast<f16x4*>(d)[i] = h;
  }
}

// ---------------- QKV projection GEMM ----------------
// C[r][c] = sum_k A[r][k] * W[c][k] + bias[c]
// A: [4096][1024] f16, W: [1024][1024] f16 (torch [out,in]).
// mode 0: Q -> [4096][1024]; mode 1: K -> [4096][1024];
// mode 2: V -> transposed Vt[b][h][dd][s]  ([B*H][64][2048]), 8B packed stores
__global__ __launch_bounds__(256)
void qkv_gemm(const f16* __restrict__ dec_h, const f16* __restrict__ enc_h,
              const f16* __restrict__ Wqh, const f16* __restrict__ Wkh, const f16* __restrict__ Wvh,
              const float* __restrict__ bq, const float* __restrict__ bk, const float* __restrict__ bv,
              f16* __restrict__ Qh, f16* __restrict__ Kh, f16* __restrict__ Vth)
{
  __shared__ f16 Ash[128 * 64];   // [row][k]  row stride 128B
  __shared__ f16 Bsh[128 * 64];   // [n][k]

  const int mode = blockIdx.z;
  const f16* A     = (mode == 0) ? dec_h : enc_h;
  const f16* W     = (mode == 0) ? Wqh : (mode == 1) ? Wkh : Wvh;
  const float* bias= (mode == 0) ? bq  : (mode == 1) ? bk  : bv;
  f16* out         = (mode == 0) ? Qh  : (mode == 1) ? Kh  : Vth;

  const int tid  = threadIdx.x;
  const int lane = tid & 63;
  const int wave = tid >> 6;
  const int wr = wave >> 1, wc = wave & 1;   // 2x2 waves, each owns 64x64 of C
  const int bm = blockIdx.x, bn = blockIdx.y;
  const int l15 = lane & 15, lg = lane >> 4;

  f32x4 acc[4][4] = {};

  for (int k0 = 0; k0 < D_MODEL; k0 += 64) {
    __syncthreads();
#pragma unroll
    for (int it = 0; it < 4; ++it) {
      int off = it * 4096 + tid * 16;      // byte offset in 16KB tile
      int row = off >> 7, colb = off & 127;
      gload_lds16((const char*)A + (size_t)(bm*128 + row) * 2048 + k0*2 + colb,
                  (char*)Ash + off);
      gload_lds16((const char*)W + (size_t)(bn*128 + row) * 2048 + k0*2 + colb,
                  (char*)Bsh + off);
    }
    asm volatile("s_waitcnt vmcnt(0)" ::: "memory");
    __syncthreads();
#pragma unroll
    for (int ks = 0; ks < 2; ++ks) {
      f16x8 af[4], bf[4];
#pragma unroll
      for (int m = 0; m < 4; ++m)
        af[m] = *reinterpret_cast<const f16x8*>((const char*)Ash + (wr*64 + m*16 + l15)*128 + ks*64 + lg*16);
#pragma unroll
      for (int n = 0; n < 4; ++n)
        bf[n] = *reinterpret_cast<const f16x8*>((const char*)Bsh + (wc*64 + n*16 + l15)*128 + ks*64 + lg*16);
#pragma unroll
      for (int m = 0; m < 4; ++m)
#pragma unroll
        for (int n = 0; n < 4; ++n)
          acc[m][n] = __builtin_amdgcn_mfma_f32_16x16x32_f16(af[m], bf[n], acc[m][n], 0, 0, 0);
    }
  }

  // epilogue: C/D layout col = lane&15, row = (lane>>4)*4 + j   [m89-verified]
#pragma unroll
  for (int m = 0; m < 4; ++m) {
    int rowg = bm*128 + wr*64 + m*16 + lg*4;
#pragma unroll
    for (int n = 0; n < 4; ++n) {
      int colg = bn*128 + wc*64 + n*16 + l15;
      float bvv = bias[colg];
      if (mode < 2) {
#pragma unroll
        for (int j = 0; j < 4; ++j)
          out[(size_t)(rowg + j) * D_MODEL + colg] = (f16)(acc[m][n][j] + bvv);
      } else {
        // Vt[(b*16+h)*64+dd][s], s = rowg..rowg+3 consecutive -> one 8B store
        int b = rowg >> 11, s = rowg & 2047;
        int hh = colg >> 6, dd = colg & 63;
        f16x4 pv;
#pragma unroll
        for (int j = 0; j < 4; ++j) pv[j] = (f16)(acc[m][n][j] + bvv);
        *reinterpret_cast<f16x4*>(out + (((size_t)((b*NHEAD + hh)*DH + dd)) << 11) + s) = pv;
      }
    }
  }
}

// ---------------- flash attention v4 ----------------
// Swapped QK^T (S^T = mfma(K,Q)) -> per-lane softmax (q = lane&15), packed P,
// defer-max (THR=8), reg-staged K/V (global->reg->LDS, plain barriers).
// Q,K: [4096][1024] f16. Vt: [B*H][64][2048] f16. Z: [B*H][2048][64] f32.
// NOTE: reference applies NO 1/sqrt(dh) scaling.
__global__ __launch_bounds__(256, 4)
void attn_kernel(const f16* __restrict__ Q, const f16* __restrict__ K,
                 const f16* __restrict__ Vt, float* __restrict__ Z)
{
  __shared__ f16 Klds[64 * 64];       // [kv][d]   128B rows, XOR-swizzled
  __shared__ f16 Vlds[64 * 64];       // [dd][kv]  128B rows, XOR-swizzled
  __shared__ f16 Plds[4][16 * 64];    // per-wave [q][kk], XOR-swizzled

  const int tid = threadIdx.x, lane = tid & 63, wave = tid >> 6;
  const int l15 = lane & 15, lg = lane >> 4;
  const int qb = blockIdx.x;          // 0..31 (q block of 64)
  const int bh = blockIdx.y;          // 0..31
  const int b = bh >> 4, h = bh & 15;

  // Q fragment (B operand of swapped QK; A operand pattern = same bytes):
  // lane holds Q[q0+l15][ks*32 + lg*8 + 0..7]
  const int qrow = qb*64 + wave*16 + l15;
  f16x8 qf[2];
#pragma unroll
  for (int ks = 0; ks < 2; ++ks)
    qf[ks] = *reinterpret_cast<const f16x8*>(Q + ((size_t)(b*SEQ + qrow)*D_MODEL + h*DH + ks*32 + lg*8));

  f32x4 oacc[4] = {};
  float mrun = -__builtin_inff();     // per-lane: running max for q = l15
  float lrun = 0.f;                   // per-lane: running denom for q = l15

  const char* Kbase = (const char*)(K  + ((size_t)b*SEQ*D_MODEL + h*DH));   // + kv*2048B
  const char* Vbase = (const char*)(Vt + ((size_t)bh*DH*SEQ));              // + dd*4096B + s*2B

  // -------- reg staging (T14): global -> regs (linear), later ds_write (swizzled)
  uint4 kr0, kr1, vr0, vr1;
  const int off0 = tid*16,        r0 = off0 >> 7, c0 = off0 & 127;
  const int off1 = 4096 + tid*16, r1 = off1 >> 7, c1 = off1 & 127;
  const int s0 = off0 ^ ((r0 & 7) << 4);
  const int s1 = off1 ^ ((r1 & 7) << 4);

  auto LOADG = [&](int kb) {
    kr0 = *reinterpret_cast<const uint4*>(Kbase + (size_t)(kb*64 + r0)*2048 + c0);
    vr0 = *reinterpret_cast<const uint4*>(Vbase + (size_t)r0*4096 + kb*128 + c0);
    kr1 = *reinterpret_cast<const uint4*>(Kbase + (size_t)(kb*64 + r1)*2048 + c1);
    vr1 = *reinterpret_cast<const uint4*>(Vbase + (size_t)r1*4096 + kb*128 + c1);
  };
  auto WRITELDS = [&]() {
    *reinterpret_cast<uint4*>((char*)Klds + s0) = kr0;
    *reinterpret_cast<uint4*>((char*)Vlds + s0) = vr0;
    *reinterpret_cast<uint4*>((char*)Klds + s1) = kr1;
    *reinterpret_cast<uint4*>((char*)Vlds + s1) = vr1;
  };

  LOADG(0);
  WRITELDS();
  __syncthreads();

  for (int kb = 0; kb < SEQ/64; ++kb) {
    if (kb + 1 < SEQ/64) LOADG(kb + 1);   // latency hides under compute below

    // S^T = K Q^T : sacc[n] tile has col=q=l15, row kk = n*16 + lg*4 + j
    f32x4 sacc[4] = {};
#pragma unroll
    for (int ks = 0; ks < 2; ++ks) {
#pragma unroll
      for (int n = 0; n < 4; ++n) {
        int r = n*16 + l15;
        f16x8 kf = *reinterpret_cast<const f16x8*>(
            (const char*)Klds + r*128 + ((ks*64 + lg*16) ^ ((r & 7) << 4)));
        sacc[n] = __builtin_amdgcn_mfma_f32_16x16x32_f16(kf, qf[ks], sacc[n], 0, 0, 0);
      }
    }

    // per-lane row max over this lane's 16 kk values, then 2 cross-group rounds
    float mt = fmaxf(fmaxf(sacc[0][0], sacc[0][1]), fmaxf(sacc[0][2], sacc[0][3]));
#pragma unroll
    for (int n = 1; n < 4; ++n)
      mt = fmaxf(mt, fmaxf(fmaxf(sacc[n][0], sacc[n][1]), fmaxf(sacc[n][2], sacc[n][3])));
    mt = fmaxf(mt, __shfl_xor(mt, 16));
    mt = fmaxf(mt, __shfl_xor(mt, 32));

    // defer-max (T13): only rescale when some row grew past THR=8
    if (!__all(mt <= mrun + 8.f)) {
      float mn = fmaxf(mrun, mt);
      float sc = __expf(mrun - mn);
      mrun = mn;
      lrun *= sc;
#pragma unroll
      for (int j = 0; j < 4; ++j) {
        // oacc rows are q = lg*4+j; fetch sc from that q's owner lane (same group)
        float scJ = __shfl(sc, (lane & 48) | (((lane >> 4) << 2) + j), 64);
#pragma unroll
        for (int n = 0; n < 4; ++n) oacc[n][j] *= scJ;
      }
    }

    // P = exp(S - mrun) (bounded by e^8), packed 4-wide writes along kk
    float rs = 0.f;
#pragma unroll
    for (int n = 0; n < 4; ++n) {
      f16x4 pp;
#pragma unroll
      for (int j = 0; j < 4; ++j) {
        float p = __expf(sacc[n][j] - mrun);
        rs += p;
        pp[j] = (f16)p;
      }
      // P[q=l15][kk = n*16 + lg*4 + j] -> byte l15*128 + (n*32 + lg*8 + 2j) ^ swz
      *reinterpret_cast<f16x4*>((char*)&Plds[wave][0] + l15*128 +
                                ((n*32 + lg*8) ^ ((l15 & 7) << 4))) = pp;
    }
    rs += __shfl_xor(rs, 16);
    rs += __shfl_xor(rs, 32);
    lrun += rs;

    // O += P @ V  (A = P rows q=l15; B = V^T rows d; layouts unchanged from R3)
#pragma unroll
    for (int ks = 0; ks < 2; ++ks) {
      f16x8 pf = *reinterpret_cast<const f16x8*>(
          (const char*)&Plds[wave][0] + l15*128 + ((ks*64 + lg*16) ^ ((l15 & 7) << 4)));
#pragma unroll
      for (int n = 0; n < 4; ++n) {
        int r = n*16 + l15;
        f16x8 vf = *reinterpret_cast<const f16x8*>(
            (const char*)Vlds + r*128 + ((ks*64 + lg*16) ^ ((r & 7) << 4)));
        oacc[n] = __builtin_amdgcn_mfma_f32_16x16x32_f16(pf, vf, oacc[n], 0, 0, 0);
      }
    }

    __syncthreads();                     // all waves done reading K/V tile kb
    if (kb + 1 < SEQ/64) WRITELDS();     // regs(kb+1) -> LDS (compiler waits vmcnt)
    __syncthreads();                     // tile kb+1 visible
  }

  // epilogue: divide by denom of row q = lg*4+j (owner lane l15' = q, same group)
  float lJ[4];
#pragma unroll
  for (int j = 0; j < 4; ++j)
    lJ[j] = __shfl(lrun, (lane & 48) | (((lane >> 4) << 2) + j), 64);
#pragma unroll
  for (int n = 0; n < 4; ++n)
#pragma unroll
    for (int j = 0; j < 4; ++j) {
      float v = oacc[n][j] / lJ[j];
      Z[((size_t)bh*SEQ + qb*64 + wave*16 + lg*4 + j)*DH + n*16 + l15] = v;
    }
}

// ---------------- residual + LayerNorm with the raw-memory reshape gather ----------------
// x[b,sq,d] = Z[b*16 + (sq>>7)][((sq&127)<<4) | (d>>6)][d&63] + decoded[b,sq,d]
__global__ __launch_bounds__(256)
void ln_kernel(const float* __restrict__ Z, const float* __restrict__ dec,
               const float* __restrict__ gamma, const float* __restrict__ beta,
               float* __restrict__ out)
{
  const int row = blockIdx.x;            // 0..4095 (b*2048 + sq)
  const int b = row >> 11, sq = row & 2047;
  const int h = sq >> 7;
  const int qbase = (sq & 127) << 4;
  const int t = threadIdx.x;
  const int d = t * 4;
  const int qi = qbase + (d >> 6);

  float4 z4 = *reinterpret_cast<const float4*>(Z + ((size_t)(b*NHEAD + h)*SEQ + qi)*DH + (d & 63));
  float4 dv = *reinterpret_cast<const float4*>(dec + (size_t)row*D_MODEL + d);
  float x0 = z4.x + dv.x, x1 = z4.y + dv.y, x2 = z4.z + dv.z, x3 = z4.w + dv.w;

  float s  = x0 + x1 + x2 + x3;
  float ss = x0*x0 + x1*x1 + x2*x2 + x3*x3;
#pragma unroll
  for (int off = 1; off < 64; off <<= 1) { s += __shfl_xor(s, off); ss += __shfl_xor(ss, off); }

  __shared__ float red[8];
  int wave = t >> 6, lane = t & 63;
  if (lane == 0) { red[wave] = s; red[wave + 4] = ss; }
  __syncthreads();
  s  = red[0] + red[1] + red[2] + red[3];
  ss = red[4] + red[5] + red[6] + red[7];

  float mean = s * (1.f/1024.f);
  float var  = ss * (1.f/1024.f) - mean*mean;
  float rstd = rsqrtf(var + 1e-5f);

  float4 g4 = *reinterpret_cast<const float4*>(gamma + d);
  float4 b4 = *reinterpret_cast<const float4*>(beta + d);
  float4 o;
  o.x = (x0 - mean)*rstd*g4.x + b4.x;
  o.y = (x1 - mean)*rstd*g4.y + b4.y;
  o.z = (x2 - mean)*rstd*g4.z + b4.z;
  o.w = (x3 - mean)*rstd*g4.w + b4.w;
  *reinterpret_cast<float4*>(out + (size_t)row*D_MODEL + d) = o;
}

// ---------------- launch ----------------
extern "C" void kernel_launch(void* const* d_in, const int* in_sizes, int n_in,
                              void* d_out, int out_size, void* d_ws, size_t ws_size,
                              hipStream_t stream) {
  const float* enc   = (const float*)d_in[0];
  const float* dec   = (const float*)d_in[1];
  const float* Wq    = (const float*)d_in[2];
  const float* bq    = (const float*)d_in[3];
  const float* Wk    = (const float*)d_in[4];
  const float* bk    = (const float*)d_in[5];
  const float* Wv    = (const float*)d_in[6];
  const float* bv    = (const float*)d_in[7];
  const float* gamma = (const float*)d_in[8];
  const float* beta  = (const float*)d_in[9];
  float* out = (float*)d_out;
  uint8_t* ws = (uint8_t*)d_ws;

  // workspace layout (62 MB total)
  f16*  enc_h = (f16*)(ws);                       // 8 MB
  f16*  dec_h = (f16*)(ws + (8u  << 20));         // 8 MB
  f16*  Wq_h  = (f16*)(ws + (16u << 20));         // 2 MB
  f16*  Wk_h  = (f16*)(ws + (18u << 20));         // 2 MB
  f16*  Wv_h  = (f16*)(ws + (20u << 20));         // 2 MB
  f16*  Qh    = (f16*)(ws + (22u << 20));         // 8 MB
  f16*  Kh    = (f16*)(ws + (30u << 20));         // 8 MB
  f16*  Vth   = (f16*)(ws + (38u << 20));         // 8 MB  [B*H][64][2048]
  float* Z    = (float*)(ws + (46u << 20));       // 16 MB [B*H][2048][64]

  const int nbig = MTOT * D_MODEL / 4;            // 1M float4 chunks
  const int nw   = D_MODEL * D_MODEL / 4;         // 256K
  cvt5_kernel<<<dim3(nbig/256, 5), 256, 0, stream>>>(
      enc, enc_h, nbig, dec, dec_h, nbig,
      Wq, Wq_h, nw, Wk, Wk_h, nw, Wv, Wv_h, nw);

  qkv_gemm<<<dim3(MTOT/128, D_MODEL/128, 3), 256, 0, stream>>>(
      dec_h, enc_h, Wq_h, Wk_h, Wv_h, bq, bk, bv, Qh, Kh, Vth);

  attn_kernel<<<dim3(SEQ/64, BATCH*NHEAD), 256, 0, stream>>>(Qh, Kh, Vth, Z);

  ln_kernel<<<MTOT, 256, 0, stream>>>(Z, dec, gamma, beta, out);
}